// Round 5
// baseline (74.550 us; speedup 1.0000x reference)
//
#include <hip/hip_runtime.h>
#include <math.h>

// B=16384, IN=64, HID=128, OUT=1, E=64, NMAP=1000 (fp32 in/out; bf16 MFMA inside)
#define B_N    16384
#define IN_D   64
#define HID_D  128
#define E_N    64
#define SB_N   64                  // routing scan-blocks, 256 samples each
#define CAP_BE 48                  // cap per (scan-block, expert); mean ~4, +15 sigma safe
#define GRP    4                   // scan-blocks merged per compute block
#define NGRP   (SB_N / GRP)        // 16 -> Kb grid = 64 * 16 = 1024 blocks
#define CAPC   (GRP * CAP_BE)      // 192 samples max per compute block

// ws layout (bytes); ws is re-poisoned 0xAA every iter -> Ka rewrites all of it
#define FRAG_OFF  0
#define FRAG_SZ   (E_N * IN_D * HID_D * 2)        // 1 MB bf16 B-fragments
#define CNT_OFF   (FRAG_OFF + FRAG_SZ)
#define CNT_SZ    (SB_N * E_N * 4)                // 16 KB counts
#define LIST_OFF  (CNT_OFF + CNT_SZ)              // 768 KB lists

typedef __attribute__((ext_vector_type(8))) short v8s;   // 8 bf16 (4 VGPRs)
typedef __attribute__((ext_vector_type(4))) float v4f;   // MFMA C/D

__device__ __forceinline__ short f2bf(float f) {         // fp32 -> bf16, RNE
    unsigned int u = __float_as_uint(f);
    u += 0x7fffu + ((u >> 16) & 1u);
    return (short)(u >> 16);
}

// ---- Ka: blocks [0,64) route samples; blocks [64,128) pre-build bf16 B-frags ----
// Frag order matches Kb's (wave,lane) MFMA layout: frag index
// f = ((w*2+nt)*2+kh)*64 + lane holds B[n=16*nt+ (lane&15)][k=32*kh+8*(lane>>4)+j].
__global__ __launch_bounds__(256) void ka_prep(
    const int* __restrict__ num, const int* __restrict__ c,
    const float* __restrict__ W1, unsigned char* __restrict__ ws)
{
    const int tid = threadIdx.x;
    if (blockIdx.x < SB_N) {
        __shared__ int lcnt[E_N];
        __shared__ int llist[E_N * CAP_BE];
        int* cnt  = (int*)(ws + CNT_OFF);
        int* list = (int*)(ws + LIST_OFF);
        const int b = blockIdx.x;
        if (tid < E_N) lcnt[tid] = 0;
        const int s = b * 256 + tid;
        const int e = c[num[s]];
        __syncthreads();
        int p = atomicAdd(&lcnt[e], 1);
        if (p < CAP_BE) llist[e * CAP_BE + p] = s;
        __syncthreads();
        if (tid < E_N) cnt[b * E_N + tid] = min(lcnt[tid], CAP_BE);
        for (int j = tid; j < E_N * CAP_BE; j += 256)   // unconditional, coalesced;
            list[b * E_N * CAP_BE + j] = llist[j];      // Kb only reads valid slots
    } else {
        const int e = blockIdx.x - SB_N;
        const float* W1e = W1 + (size_t)e * (IN_D * HID_D);
        // thread builds 4 consecutive frags f0..f0+3 = 4 lanes of one (w,nt,kh)
        const int f0    = tid * 4;
        const int w     = f0 >> 8, nt = (f0 >> 7) & 1, kh = (f0 >> 6) & 1;
        const int quad  = (f0 >> 4) & 3;
        const int hbase = 32 * w + 16 * nt + (f0 & 15);   // (f0&15) in {0,4,8,12}
        v8s t[4];
        #pragma unroll
        for (int j = 0; j < 8; ++j) {
            const float4 v = *(const float4*)&W1e[(32 * kh + 8 * quad + j) * HID_D + hbase];
            t[0][j] = f2bf(v.x); t[1][j] = f2bf(v.y);
            t[2][j] = f2bf(v.z); t[3][j] = f2bf(v.w);
        }
        v8s* frag = (v8s*)(ws + FRAG_OFF) + (size_t)e * (IN_D * HID_D / 8);
        #pragma unroll
        for (int i = 0; i < 4; ++i) frag[f0 + i] = t[i];
    }
}

// ---- Kb: block (e, g) computes expert e's samples from scan-blocks [4g,4g+4) ----
__global__ __launch_bounds__(256) void kb_compute(
    const float* __restrict__ x,
    const float* __restrict__ b1, const float* __restrict__ W2,
    const float* __restrict__ b2,
    const unsigned char* __restrict__ ws, float* __restrict__ out)
{
    __shared__ int   s_c[GRP], s_pfx[GRP + 1];
    __shared__ int   s_list[CAPC];
    __shared__ float s_yw[4][CAPC];

    const int tid = threadIdx.x;
    const int e   = blockIdx.x & (E_N - 1);
    const int g   = blockIdx.x >> 6;
    const int* cnt  = (const int*)(ws + CNT_OFF);
    const int* list = (const int*)(ws + LIST_OFF);

    if (tid < GRP) s_c[tid] = cnt[(g * GRP + tid) * E_N + e];
    __syncthreads();
    if (tid == 0) {
        int a = 0;
        for (int i = 0; i < GRP; ++i) { s_pfx[i] = a; a += s_c[i]; }
        s_pfx[GRP] = a;
    }
    __syncthreads();
    const int total = s_pfx[GRP];

    for (int j = tid; j < GRP * CAP_BE; j += 256) {
        const int sub = j / CAP_BE, slot = j - sub * CAP_BE;
        if (slot < s_c[sub])
            s_list[s_pfx[sub] + slot] =
                list[((g * GRP + sub) * E_N + e) * CAP_BE + slot];
    }

    // B-frags: 4 coalesced dwordx4 per lane from precomputed ws (no scatter, no f2bf)
    const int wave = __builtin_amdgcn_readfirstlane(tid >> 6);
    const int lane = tid & 63, l16 = lane & 15, quad = lane >> 4;
    const v8s* frag = (const v8s*)(ws + FRAG_OFF) + (size_t)e * (IN_D * HID_D / 8);
    v8s bfrag[2][2];
    #pragma unroll
    for (int nt = 0; nt < 2; ++nt)
        #pragma unroll
        for (int kh = 0; kh < 2; ++kh)
            bfrag[nt][kh] = frag[((wave * 2 + nt) * 2 + kh) * 64 + lane];

    const int   h0   = 32 * wave + l16, h1 = h0 + 16;
    const float b1v0 = b1[e * HID_D + h0], b1v1 = b1[e * HID_D + h1];
    const float w2v0 = W2[e * HID_D + h0], w2v1 = W2[e * HID_D + h1];
    const float b2v  = b2[e];
    __syncthreads();

    const int ntiles = (total + 15) >> 4;
    for (int mt = 0; mt < ntiles; ++mt) {
        const int idx = mt * 16 + l16;
        const int s   = s_list[min(idx, total - 1)];
        const float4* row = (const float4*)(x + (size_t)s * IN_D);

        // A[m=l16][k=quad*8+j] (+32 second k-half)
        const float4 f0 = row[2 * quad],     f1 = row[2 * quad + 1];
        const float4 f2 = row[8 + 2 * quad], f3 = row[8 + 2 * quad + 1];
        v8s a0, a1;
        a0[0]=f2bf(f0.x); a0[1]=f2bf(f0.y); a0[2]=f2bf(f0.z); a0[3]=f2bf(f0.w);
        a0[4]=f2bf(f1.x); a0[5]=f2bf(f1.y); a0[6]=f2bf(f1.z); a0[7]=f2bf(f1.w);
        a1[0]=f2bf(f2.x); a1[1]=f2bf(f2.y); a1[2]=f2bf(f2.z); a1[3]=f2bf(f2.w);
        a1[4]=f2bf(f3.x); a1[5]=f2bf(f3.y); a1[6]=f2bf(f3.z); a1[7]=f2bf(f3.w);

        v4f acc0 = {0.f, 0.f, 0.f, 0.f};
        v4f acc1 = {0.f, 0.f, 0.f, 0.f};
        acc0 = __builtin_amdgcn_mfma_f32_16x16x32_bf16(a0, bfrag[0][0], acc0, 0, 0, 0);
        acc0 = __builtin_amdgcn_mfma_f32_16x16x32_bf16(a1, bfrag[0][1], acc0, 0, 0, 0);
        acc1 = __builtin_amdgcn_mfma_f32_16x16x32_bf16(a0, bfrag[1][0], acc1, 0, 0, 0);
        acc1 = __builtin_amdgcn_mfma_f32_16x16x32_bf16(a1, bfrag[1][1], acc1, 0, 0, 0);

        // C/D: col(h)=lane&15, row(sample)=quad*4+r. Fused bias/ReLU/W2 + h-reduce.
        #pragma unroll
        for (int r = 0; r < 4; ++r) {
            float v = fmaxf(acc0[r] + b1v0, 0.f) * w2v0
                    + fmaxf(acc1[r] + b1v1, 0.f) * w2v1;
            v += __shfl_xor(v, 1);
            v += __shfl_xor(v, 2);
            v += __shfl_xor(v, 4);
            v += __shfl_xor(v, 8);
            if (l16 == 0) s_yw[wave][mt * 16 + quad * 4 + r] = v;
        }
    }
    __syncthreads();

    for (int i = tid; i < total; i += 256) {
        const float t = s_yw[0][i] + s_yw[1][i] + s_yw[2][i] + s_yw[3][i] + b2v;
        out[s_list[i]] = 1.0f / (1.0f + expf(-t));
    }
}

extern "C" void kernel_launch(void* const* d_in, const int* in_sizes, int n_in,
                              void* d_out, int out_size, void* d_ws, size_t ws_size,
                              hipStream_t stream)
{
    const float* x   = (const float*)d_in[0];
    const int*   num = (const int*)  d_in[1];
    const int*   c   = (const int*)  d_in[2];
    const float* W1  = (const float*)d_in[3];
    const float* b1  = (const float*)d_in[4];
    const float* W2  = (const float*)d_in[5];
    const float* b2  = (const float*)d_in[6];
    float*       out = (float*)d_out;
    unsigned char* ws = (unsigned char*)d_ws;

    ka_prep   <<<dim3(SB_N + E_N),   dim3(256), 0, stream>>>(num, c, W1, ws);
    kb_compute<<<dim3(E_N * NGRP),   dim3(256), 0, stream>>>(x, b1, W2, b2, ws, out);
}

// Round 6
// 74.224 us; speedup vs baseline: 1.0044x; 1.0044x over previous
//
#include <hip/hip_runtime.h>
#include <math.h>

// B=16384, IN=64, HID=128, OUT=1, E=64, NMAP=1000 (fp32 in/out; bf16 MFMA inside)
#define B_N    16384
#define IN_D   64
#define HID_D  128
#define E_N    64
#define SB_N   64                  // routing scan-blocks, 256 samples each
#define CAP_BE 48                  // cap per (scan-block, expert); mean ~4
#define GRP    4                   // scan-blocks merged per compute block
#define NGRP   (SB_N / GRP)        // 16 -> Kb grid = 64 * 16 = 1024 blocks
#define CAPC   (GRP * CAP_BE)      // 192 samples max per compute block

// ws layout (bytes); ws re-poisoned 0xAA every iter -> Ka rewrites all it uses.
// Counts transposed (e-major) and lists (e,sb)-major so Kb's prologue is one
// broadcast int4 + one contiguous 768B list read (R5 had a thread-0 serial
// prefix + extra LDS round-trip on the critical chain).
#define FRAG_OFF  0
#define FRAG_SZ   (E_N * IN_D * HID_D * 2)        // 1 MB bf16 B-fragments
#define CNT_OFF   (FRAG_OFF + FRAG_SZ)
#define CNT_SZ    (E_N * SB_N * 4)                // 16 KB counts, cnt[e*SB_N+sb]
#define LIST_OFF  (CNT_OFF + CNT_SZ)              // lists[(e*SB_N+sb)*CAP_BE + slot]

typedef __attribute__((ext_vector_type(8))) short v8s;   // 8 bf16 (4 VGPRs)
typedef __attribute__((ext_vector_type(4))) float v4f;   // MFMA C/D

__device__ __forceinline__ short f2bf(float f) {         // fp32 -> bf16, RNE
    unsigned int u = __float_as_uint(f);
    u += 0x7fffu + ((u >> 16) & 1u);
    return (short)(u >> 16);
}

// ---- Ka: blocks [0,64) route samples; blocks [64,128) pre-build bf16 B-frags ----
__global__ __launch_bounds__(256) void ka_prep(
    const int* __restrict__ num, const int* __restrict__ c,
    const float* __restrict__ W1, unsigned char* __restrict__ ws)
{
    const int tid = threadIdx.x;
    if (blockIdx.x < SB_N) {
        __shared__ int lcnt[E_N];
        __shared__ int llist[E_N * CAP_BE];
        int* cnt  = (int*)(ws + CNT_OFF);
        int* list = (int*)(ws + LIST_OFF);
        const int b = blockIdx.x;
        if (tid < E_N) lcnt[tid] = 0;
        const int s = b * 256 + tid;
        const int e = c[num[s]];
        __syncthreads();
        int p = atomicAdd(&lcnt[e], 1);
        if (p < CAP_BE) llist[e * CAP_BE + p] = s;
        __syncthreads();
        if (tid < E_N) cnt[tid * SB_N + b] = min(lcnt[tid], CAP_BE);
        for (int j = tid; j < E_N * CAP_BE; j += 256) {  // unconditional; Kb reads
            const int e2 = j / CAP_BE, slot = j - e2 * CAP_BE;  // only valid slots
            list[(e2 * SB_N + b) * CAP_BE + slot] = llist[j];
        }
    } else {
        const int e = blockIdx.x - SB_N;
        const float* W1e = W1 + (size_t)e * (IN_D * HID_D);
        // thread builds 4 consecutive frags f0..f0+3 = 4 lanes of one (w,nt,kh);
        // frag f = ((w*2+nt)*2+kh)*64 + lane holds B[n=16nt+(lane&15)][k=32kh+8q+j]
        const int f0    = tid * 4;
        const int w     = f0 >> 8, nt = (f0 >> 7) & 1, kh = (f0 >> 6) & 1;
        const int quad  = (f0 >> 4) & 3;
        const int hbase = 32 * w + 16 * nt + (f0 & 15);
        v8s t[4];
        #pragma unroll
        for (int j = 0; j < 8; ++j) {
            const float4 v = *(const float4*)&W1e[(32 * kh + 8 * quad + j) * HID_D + hbase];
            t[0][j] = f2bf(v.x); t[1][j] = f2bf(v.y);
            t[2][j] = f2bf(v.z); t[3][j] = f2bf(v.w);
        }
        v8s* frag = (v8s*)(ws + FRAG_OFF) + (size_t)e * (IN_D * HID_D / 8);
        #pragma unroll
        for (int i = 0; i < 4; ++i) frag[f0 + i] = t[i];
    }
}

// ---- Kb: block (e, g) computes expert e's samples from scan-blocks [4g,4g+4) ----
__global__ __launch_bounds__(256) void kb_compute(
    const float* __restrict__ x,
    const float* __restrict__ b1, const float* __restrict__ W2,
    const float* __restrict__ b2,
    const unsigned char* __restrict__ ws, float* __restrict__ out)
{
    __shared__ int   s_list[CAPC];
    __shared__ float s_yw[4][CAPC];

    const int tid = threadIdx.x;
    const int e   = blockIdx.x & (E_N - 1);
    const int g   = blockIdx.x >> 6;
    const int* cnt  = (const int*)(ws + CNT_OFF);
    const int* list = (const int*)(ws + LIST_OFF);

    // one broadcast int4 -> per-thread register prefix (no LDS, no serial loop)
    const int4 cv = *(const int4*)&cnt[e * SB_N + g * GRP];
    const int  p0 = 0, p1 = cv.x, p2 = cv.x + cv.y, p3 = p2 + cv.z;
    const int  total = p3 + cv.w;
    const int  pfx[GRP] = { p0, p1, p2, p3 };
    const int  cc[GRP]  = { cv.x, cv.y, cv.z, cv.w };

    // 4 sub-lists are contiguous 768B at (e, 4g): single coalesced read
    const int* lsrc = &list[(e * SB_N + g * GRP) * CAP_BE];
    #pragma unroll
    for (int rep = 0; rep < (GRP * CAP_BE + 255) / 256; ++rep) {
        const int j = rep * 256 + tid;
        if (j < GRP * CAP_BE) {
            const int sub = j / CAP_BE, slot = j - sub * CAP_BE;
            if (slot < cc[sub]) s_list[pfx[sub] + slot] = lsrc[j];
        }
    }

    // B-frags: 4 coalesced dwordx4 per lane from precomputed ws
    const int wave = __builtin_amdgcn_readfirstlane(tid >> 6);
    const int lane = tid & 63, l16 = lane & 15, quad = lane >> 4;
    const v8s* frag = (const v8s*)(ws + FRAG_OFF) + (size_t)e * (IN_D * HID_D / 8);
    v8s bfrag[2][2];
    #pragma unroll
    for (int nt = 0; nt < 2; ++nt)
        #pragma unroll
        for (int kh = 0; kh < 2; ++kh)
            bfrag[nt][kh] = frag[((wave * 2 + nt) * 2 + kh) * 64 + lane];

    const int   h0   = 32 * wave + l16, h1 = h0 + 16;
    const float b1v0 = b1[e * HID_D + h0], b1v1 = b1[e * HID_D + h1];
    const float w2v0 = W2[e * HID_D + h0], w2v1 = W2[e * HID_D + h1];
    const float b2v  = b2[e];
    __syncthreads();

    const int ntiles = (total + 15) >> 4;
    for (int mt = 0; mt < ntiles; ++mt) {
        const int idx = mt * 16 + l16;
        const int s   = s_list[min(idx, total - 1)];
        const float4* row = (const float4*)(x + (size_t)s * IN_D);

        // A[m=l16][k=quad*8+j] (+32 second k-half)
        const float4 f0 = row[2 * quad],     f1 = row[2 * quad + 1];
        const float4 f2 = row[8 + 2 * quad], f3 = row[8 + 2 * quad + 1];
        v8s a0, a1;
        a0[0]=f2bf(f0.x); a0[1]=f2bf(f0.y); a0[2]=f2bf(f0.z); a0[3]=f2bf(f0.w);
        a0[4]=f2bf(f1.x); a0[5]=f2bf(f1.y); a0[6]=f2bf(f1.z); a0[7]=f2bf(f1.w);
        a1[0]=f2bf(f2.x); a1[1]=f2bf(f2.y); a1[2]=f2bf(f2.z); a1[3]=f2bf(f2.w);
        a1[4]=f2bf(f3.x); a1[5]=f2bf(f3.y); a1[6]=f2bf(f3.z); a1[7]=f2bf(f3.w);

        v4f acc0 = {0.f, 0.f, 0.f, 0.f};
        v4f acc1 = {0.f, 0.f, 0.f, 0.f};
        acc0 = __builtin_amdgcn_mfma_f32_16x16x32_bf16(a0, bfrag[0][0], acc0, 0, 0, 0);
        acc0 = __builtin_amdgcn_mfma_f32_16x16x32_bf16(a1, bfrag[0][1], acc0, 0, 0, 0);
        acc1 = __builtin_amdgcn_mfma_f32_16x16x32_bf16(a0, bfrag[1][0], acc1, 0, 0, 0);
        acc1 = __builtin_amdgcn_mfma_f32_16x16x32_bf16(a1, bfrag[1][1], acc1, 0, 0, 0);

        // C/D: col(h)=lane&15, row(sample)=quad*4+r. Fused bias/ReLU/W2 + h-reduce.
        #pragma unroll
        for (int r = 0; r < 4; ++r) {
            float v = fmaxf(acc0[r] + b1v0, 0.f) * w2v0
                    + fmaxf(acc1[r] + b1v1, 0.f) * w2v1;
            v += __shfl_xor(v, 1);
            v += __shfl_xor(v, 2);
            v += __shfl_xor(v, 4);
            v += __shfl_xor(v, 8);
            if (l16 == 0) s_yw[wave][mt * 16 + quad * 4 + r] = v;
        }
    }
    __syncthreads();

    for (int i = tid; i < total; i += 256) {
        const float t = s_yw[0][i] + s_yw[1][i] + s_yw[2][i] + s_yw[3][i] + b2v;
        out[s_list[i]] = 1.0f / (1.0f + expf(-t));
    }
}

extern "C" void kernel_launch(void* const* d_in, const int* in_sizes, int n_in,
                              void* d_out, int out_size, void* d_ws, size_t ws_size,
                              hipStream_t stream)
{
    const float* x   = (const float*)d_in[0];
    const int*   num = (const int*)  d_in[1];
    const int*   c   = (const int*)  d_in[2];
    const float* W1  = (const float*)d_in[3];
    const float* b1  = (const float*)d_in[4];
    const float* W2  = (const float*)d_in[5];
    const float* b2  = (const float*)d_in[6];
    float*       out = (float*)d_out;
    unsigned char* ws = (unsigned char*)d_ws;

    ka_prep   <<<dim3(SB_N + E_N), dim3(256), 0, stream>>>(num, c, W1, ws);
    kb_compute<<<dim3(E_N * NGRP), dim3(256), 0, stream>>>(x, b1, W2, b2, ws, out);
}